// Round 7
// baseline (123.865 us; speedup 1.0000x reference)
//
#include <hip/hip_runtime.h>
#include <math.h>

// Problem constants (reference: N=250000, D=16, L=6, K=64, gamma=0.1)
#define NPOINTS 250000
#define LL 6
#define DD 16
#define KK 64
#define TPB 384            // 6 waves; wave w handles layer w for the block's 256 points
#define PTS_PER_BLOCK 256
#define NTILES 16          // 16 MFMA tiles of 16 points each

// LDS layout (byte offsets into smem), phase-aliased:
//  Phase A: musc: column j of layer l at (l*64+j)*64, 24576 B
//  Phase B: sxu: point p at p*80 (80B: hi d0-7, hi d8-15, lo d0-7, lo d8-15, pad), 20480 B
//           smc: float at SMC_OFF + (l*256+p)*4, 6144 B
//  swv: 6 floats at SWV_OFF (never aliased)
#define SMC_OFF 20480
#define SWV_OFF 26624
#define LDS_BYTES (SWV_OFF + 32)

typedef __attribute__((ext_vector_type(8))) short bf16x8;
typedef __attribute__((ext_vector_type(4))) float f32x4;
typedef __attribute__((ext_vector_type(2))) float f32x2;

#if __has_builtin(__builtin_amdgcn_exp2f)
#define EXP2F(x) __builtin_amdgcn_exp2f(x)
#else
#define EXP2F(x) exp2f(x)
#endif
#if __has_builtin(__builtin_amdgcn_logf)
#define LOG2F(x) __builtin_amdgcn_logf(x)
#else
#define LOG2F(x) log2f(x)
#endif
#if __has_builtin(__builtin_amdgcn_sqrtf)
#define SQRTF(x) __builtin_amdgcn_sqrtf(x)
#else
#define SQRTF(x) sqrtf(x)
#endif

#define C_AA   (-14.426950408889634f)   // -10 * log2(e)
#define C_GLN2 (0.06931471805599453f)   // gamma * ln(2)

// acos poly folded with SQ_C = sqrt(5*log2e) = 2.6857914 so that
// u = SQ_C * acos(clip(x)) and t2 = -u^2 + aa = log2-arg of the exp term.
#define AC3 (-0.05030299f)
#define AC2 (0.19944957f)
#define AC1 (-0.56969503f)
#define AC0 (4.2186499f)
#define PI_HAT (8.4376625f)             // SQ_C * pi
#define CLIP_C (1.0f - 1e-7f)

__device__ __forceinline__ f32x2 s2(float v) { f32x2 r; r.x = v; r.y = v; return r; }

__device__ __forceinline__ ushort bf16_rne(float f) {
  unsigned u = __float_as_uint(f);
  unsigned r = u + 0x7FFFu + ((u >> 16) & 1u);
  return (ushort)(r >> 16);
}

// packed pair: exp2( -5*log2e*acos(clip(x))^2 + aa ), aa pre-splat
__device__ __forceinline__ f32x2 term2(f32x2 x, f32x2 aa) {
  // symmetric clip: ax = min(|x|, 1-1e-7); sign from raw x
  f32x2 ax = __builtin_elementwise_min(__builtin_elementwise_abs(x), s2(CLIP_C));
  f32x2 pp = __builtin_elementwise_fma(ax, s2(AC3), s2(AC2));   // v_pk_fma_f32
  pp = __builtin_elementwise_fma(pp, ax, s2(AC1));
  pp = __builtin_elementwise_fma(pp, ax, s2(AC0));
  f32x2 om = s2(1.0f) - ax;                                      // v_pk_add_f32
  f32x2 sq; sq.x = SQRTF(om.x); sq.y = SQRTF(om.y);
  f32x2 v = sq * pp;                                             // v_pk_mul_f32
  f32x2 u;
  u.x = (x.x < 0.0f) ? (PI_HAT - v.x) : v.x;
  u.y = (x.y < 0.0f) ? (PI_HAT - v.y) : v.y;
  f32x2 t2 = __builtin_elementwise_fma(u, -u, aa);               // v_pk_fma_f32
  f32x2 e; e.x = EXP2F(t2.x); e.y = EXP2F(t2.y);
  return e;
}

// DPP row-shift adds; after shr 1,2,4,8 lane 15 of each 16-row holds the sum.
#define DPP_ADD(S, CTRL)                                                     \
  {                                                                          \
    int _t = __builtin_amdgcn_update_dpp(0, __float_as_int(S), CTRL, 0xF,    \
                                         0xF, true);                         \
    S += __int_as_float(_t);                                                 \
  }
#define ROW_SHR1 0x111
#define ROW_SHR2 0x112
#define ROW_SHR4 0x114
#define ROW_SHR8 0x118

__global__ __launch_bounds__(TPB, 4) void
multiinf_kernel(const float* __restrict__ xs,
                const float* __restrict__ mus,    // [L, D, K]
                const float* __restrict__ alphas, // [L, K]
                const float* __restrict__ wsv,    // [L]
                float* __restrict__ out) {
  __shared__ __align__(16) char smem[LDS_BYTES];
  float* swv = (float*)(smem + SWV_OFF);
  float* smc = (float*)(smem + SMC_OFF);

  const int tid = threadIdx.x;
  const int w = tid >> 6;            // wave = layer
  const int lane = tid & 63;
  const int c = lane & 15;           // MFMA col (comp-in-block / point-in-tile)
  const int q = lane >> 4;           // quad
  const int h = q & 1;               // dim half
  const int pbase = blockIdx.x * PTS_PER_BLOCK;

  // Prefetch this thread's x point (threads 0..255) to overlap with phase A
  float xv[DD];
  {
    int gidx = pbase + tid;
    if (tid < PTS_PER_BLOCK && gidx < NPOINTS) {
      const float4* x4 = (const float4*)(xs + (size_t)gidx * DD);
#pragma unroll
      for (int j = 0; j < 4; ++j) {
        float4 a = x4[j];
        xv[j * 4 + 0] = a.x; xv[j * 4 + 1] = a.y;
        xv[j * 4 + 2] = a.z; xv[j * 4 + 3] = a.w;
      }
    } else {
#pragma unroll
      for (int d = 0; d < DD; ++d) xv[d] = 0.0f;
    }
  }

  // ---- Phase A: wave w normalizes column `lane` of layer w, splits bf16 hi/lo,
  //      writes 64B column record into musc scratch ----
  {
    const float* colp = mus + w * (DD * KK) + lane;   // stride KK over d (coalesced per d)
    float v[DD];
    float ss = 0.0f;
#pragma unroll
    for (int d = 0; d < DD; ++d) { v[d] = colp[d * KK]; ss = fmaf(v[d], v[d], ss); }
    float inv = 1.0f / sqrtf(ss);
    unsigned hw[8], lw[8];
#pragma unroll
    for (int i = 0; i < 8; ++i) {
      float a0 = v[2 * i] * inv;
      float a1 = v[2 * i + 1] * inv;
      ushort h0 = bf16_rne(a0), h1 = bf16_rne(a1);
      float hf0 = __uint_as_float((unsigned)h0 << 16);
      float hf1 = __uint_as_float((unsigned)h1 << 16);
      ushort l0 = bf16_rne(a0 - hf0), l1 = bf16_rne(a1 - hf1);
      hw[i] = (unsigned)h0 | ((unsigned)h1 << 16);
      lw[i] = (unsigned)l0 | ((unsigned)l1 << 16);
    }
    uint4* colq = (uint4*)(smem + (w * 64 + lane) * 64);
    colq[0] = make_uint4(hw[0], hw[1], hw[2], hw[3]);
    colq[1] = make_uint4(hw[4], hw[5], hw[6], hw[7]);
    colq[2] = make_uint4(lw[0], lw[1], lw[2], lw[3]);
    colq[3] = make_uint4(lw[4], lw[5], lw[6], lw[7]);
  }
  float av = C_AA * alphas[w * 64 + lane];   // alpha of column `lane`
  if (tid < LL) { float t = wsv[tid]; swv[tid] = expf(-t * t); }
  __syncthreads();

  // ---- Read B fragments into registers (resident for the whole main loop) ----
  bf16x8 Bh[4], Bl[4];
  f32x2 aa2[4];
#pragma unroll
  for (int cb = 0; cb < 4; ++cb) {
    const char* base = smem + (w * 64 + cb * 16 + c) * 64 + h * 16;
    Bh[cb] = *(const bf16x8*)(base);
    Bl[cb] = *(const bf16x8*)(base + 32);
    aa2[cb] = s2(__shfl(av, cb * 16 + c, 64));
  }
  __syncthreads();   // all frag reads done; musc region now reusable

  // ---- Phase B: stage x A-fragments (bf16 hi/lo) into sxu ----
  if (tid < PTS_PER_BLOCK) {
    unsigned hw[8], lw[8];
#pragma unroll
    for (int i = 0; i < 8; ++i) {
      ushort h0 = bf16_rne(xv[2 * i]);
      ushort h1 = bf16_rne(xv[2 * i + 1]);
      float hf0 = __uint_as_float((unsigned)h0 << 16);
      float hf1 = __uint_as_float((unsigned)h1 << 16);
      ushort l0 = bf16_rne(xv[2 * i] - hf0);
      ushort l1 = bf16_rne(xv[2 * i + 1] - hf1);
      hw[i] = (unsigned)h0 | ((unsigned)h1 << 16);
      lw[i] = (unsigned)l0 | ((unsigned)l1 << 16);
    }
    uint4* pq = (uint4*)(smem + tid * 80);
    pq[0] = make_uint4(hw[0], hw[1], hw[2], hw[3]);
    pq[1] = make_uint4(hw[4], hw[5], hw[6], hw[7]);
    pq[2] = make_uint4(lw[0], lw[1], lw[2], lw[3]);
    pq[3] = make_uint4(lw[4], lw[5], lw[6], lw[7]);
  }
  __syncthreads();

  // ---- Main loop: 2 tiles in flight per iteration (independent streams) ----
  float* smcw = smc + w * PTS_PER_BLOCK;
  bf16x8 A0 = *(const bf16x8*)(smem + (0 * 16 + c) * 80 + q * 16);
  bf16x8 A1 = *(const bf16x8*)(smem + (1 * 16 + c) * 80 + q * 16);
  for (int t = 0; t < NTILES; t += 2) {
    // prefetch the next pair's A fragments
    bf16x8 An0 = *(const bf16x8*)(smem + ((((t + 2) & 15) * 16) + c) * 80 + q * 16);
    bf16x8 An1 = *(const bf16x8*)(smem + ((((t + 3) & 15) * 16) + c) * 80 + q * 16);

    f32x2 S01a = s2(0.0f), S23a = s2(0.0f);
    f32x2 S01b = s2(0.0f), S23b = s2(0.0f);
#pragma unroll
    for (int cb = 0; cb < 4; ++cb) {
      f32x4 acc0 = {0.0f, 0.0f, 0.0f, 0.0f};
      f32x4 acc1 = {0.0f, 0.0f, 0.0f, 0.0f};
      acc0 = __builtin_amdgcn_mfma_f32_16x16x32_bf16(A0, Bh[cb], acc0, 0, 0, 0);
      acc1 = __builtin_amdgcn_mfma_f32_16x16x32_bf16(A1, Bh[cb], acc1, 0, 0, 0);
      acc0 = __builtin_amdgcn_mfma_f32_16x16x32_bf16(A0, Bl[cb], acc0, 0, 0, 0);
      acc1 = __builtin_amdgcn_mfma_f32_16x16x32_bf16(A1, Bl[cb], acc1, 0, 0, 0);
      f32x2 a01a; a01a.x = acc0[0]; a01a.y = acc0[1];
      f32x2 a23a; a23a.x = acc0[2]; a23a.y = acc0[3];
      f32x2 a01b; a01b.x = acc1[0]; a01b.y = acc1[1];
      f32x2 a23b; a23b.x = acc1[2]; a23b.y = acc1[3];
      S01a += term2(a01a, aa2[cb]);
      S01b += term2(a01b, aa2[cb]);
      S23a += term2(a23a, aa2[cb]);
      S23b += term2(a23b, aa2[cb]);
    }
    float S0a = S01a.x, S1a = S01a.y, S2a = S23a.x, S3a = S23a.y;
    float S0b = S01b.x, S1b = S01b.y, S2b = S23b.x, S3b = S23b.y;
    // sum over the 16 comp-lanes: DPP row scan; 8 independent chains interleave
    DPP_ADD(S0a, ROW_SHR1) DPP_ADD(S1a, ROW_SHR1) DPP_ADD(S2a, ROW_SHR1) DPP_ADD(S3a, ROW_SHR1)
    DPP_ADD(S0b, ROW_SHR1) DPP_ADD(S1b, ROW_SHR1) DPP_ADD(S2b, ROW_SHR1) DPP_ADD(S3b, ROW_SHR1)
    DPP_ADD(S0a, ROW_SHR2) DPP_ADD(S1a, ROW_SHR2) DPP_ADD(S2a, ROW_SHR2) DPP_ADD(S3a, ROW_SHR2)
    DPP_ADD(S0b, ROW_SHR2) DPP_ADD(S1b, ROW_SHR2) DPP_ADD(S2b, ROW_SHR2) DPP_ADD(S3b, ROW_SHR2)
    DPP_ADD(S0a, ROW_SHR4) DPP_ADD(S1a, ROW_SHR4) DPP_ADD(S2a, ROW_SHR4) DPP_ADD(S3a, ROW_SHR4)
    DPP_ADD(S0b, ROW_SHR4) DPP_ADD(S1b, ROW_SHR4) DPP_ADD(S2b, ROW_SHR4) DPP_ADD(S3b, ROW_SHR4)
    DPP_ADD(S0a, ROW_SHR8) DPP_ADD(S1a, ROW_SHR8) DPP_ADD(S2a, ROW_SHR8) DPP_ADD(S3a, ROW_SHR8)
    DPP_ADD(S0b, ROW_SHR8) DPP_ADD(S1b, ROW_SHR8) DPP_ADD(S2b, ROW_SHR8) DPP_ADD(S3b, ROW_SHR8)

    if (c == 15) {   // rows q*4+r; store raw sums, log applied in epilogue
      smcw[t * 16 + q * 4 + 0] = S0a;
      smcw[t * 16 + q * 4 + 1] = S1a;
      smcw[t * 16 + q * 4 + 2] = S2a;
      smcw[t * 16 + q * 4 + 3] = S3a;
      smcw[(t + 1) * 16 + q * 4 + 0] = S0b;
      smcw[(t + 1) * 16 + q * 4 + 1] = S1b;
      smcw[(t + 1) * 16 + q * 4 + 2] = S2b;
      smcw[(t + 1) * 16 + q * 4 + 3] = S3b;
    }
    A0 = An0;
    A1 = An1;
  }
  __syncthreads();

  // ---- Epilogue: recurrence + smooth-min, one thread per point ----
  if (tid < PTS_PER_BLOCK) {
    float F = 0.0f;
#pragma unroll
    for (int l = 0; l < LL; ++l) {
      float wv = swv[l];
      float mc = C_GLN2 * LOG2F(smc[l * PTS_PER_BLOCK + tid]);  // gamma*ln(S)
      F = fmaf(wv, fmaxf(F, 0.0f), (1.0f - wv) * mc);
    }
    int idx = pbase + tid;
    if (idx < NPOINTS) {
      float e = EXP2F(F * C_AA);              // exp(-F/0.1)
      out[idx] = C_GLN2 * LOG2F(1.0f + e);    // 0.1 * ln(1 + e)
    }
  }
}

extern "C" void kernel_launch(void* const* d_in, const int* in_sizes, int n_in,
                              void* d_out, int out_size, void* d_ws, size_t ws_size,
                              hipStream_t stream) {
  const float* xs = (const float*)d_in[0];     // [N, D]
  const float* mus = (const float*)d_in[1];    // [L, D, K]
  const float* alphas = (const float*)d_in[2]; // [L, K]
  const float* wsv = (const float*)d_in[3];    // [L]
  float* out = (float*)d_out;
  (void)d_ws; (void)ws_size;

  const int blocks = (NPOINTS + PTS_PER_BLOCK - 1) / PTS_PER_BLOCK;  // 977
  multiinf_kernel<<<blocks, TPB, 0, stream>>>(xs, mus, alphas, wsv, out);
}